// Round 1
// baseline (4646.185 us; speedup 1.0000x reference)
//
#include <hip/hip_runtime.h>
#include <hip/hip_bf16.h>
#include <cstddef>

// Problem constants
#define NT     12544   // B*T tokens
#define BATCH  64
#define TSEQ   196
#define DMODEL 2048
#define NH     32
#define NKVH   8
#define HDIM   64
#define IMLP   8192
#define QDIMC  512
#define PDIMC  128

typedef __bf16 bf16x8 __attribute__((ext_vector_type(8)));
typedef float f32x4 __attribute__((ext_vector_type(4)));

// ---------------------------------------------------------------------------
// async global->LDS, 16B per lane (dest = wave-uniform base + lane*16)
// ---------------------------------------------------------------------------
__device__ __forceinline__ void gload_lds16(const void* g, void* l) {
    __builtin_amdgcn_global_load_lds(
        (__attribute__((address_space(1))) void*)g,
        (__attribute__((address_space(3))) void*)l, 16, 0, 0);
}

// ---------------------------------------------------------------------------
// Weight pre-pack: W[K=2048, N] fp32 (row stride ldw) -> tile-packed bf16.
// Packed layout: for n-tile tn (128 wide) and k-step ks (32 deep):
//   P[(tn*64 + ks)*4096 + k2*1024 + m*8 + kin] = W[ks*32 + k2*8 + kin][tn*128+m]
// This is EXACTLY the GEMM's LDS slot order -> gload_lds src is contiguous.
// grid.x = N*K/2048 blocks (2 blocks per 4096-elem tile), 256 thr.
// All loads coalesced (lane-consecutive m), output stores coalesced 16B.
// ---------------------------------------------------------------------------
__global__ __launch_bounds__(256) void pack_cast_kernel(const float* __restrict__ W,
                                                        __hip_bfloat16* __restrict__ P,
                                                        int ldw) {
    const int bid  = blockIdx.x;
    const int tile = bid >> 1;
    const int tn   = tile >> 6;          // K fixed at 2048 -> KS = 64
    const int ks   = tile & 63;
    const int within = ((bid & 1) << 8) | threadIdx.x;   // 0..511
    const int k2 = within >> 7, m = within & 127;
    const float* src = W + (size_t)(ks * 32 + k2 * 8) * ldw + tn * 128 + m;
    union { bf16x8 v; __hip_bfloat16 h[8]; } u;
    #pragma unroll
    for (int kin = 0; kin < 8; ++kin)
        u.h[kin] = __float2bfloat16(src[(size_t)kin * ldw]);
    *(bf16x8*)(P + ((size_t)bid * 256 + threadIdx.x) * 8) = u.v;
}

// ---------------------------------------------------------------------------
// bf16 MFMA GEMM: C[M,N] = A[M,2048] @ B, B given tile-packed (see above).
// 128x128 tile, BK=32, 256 thr (4 waves, each 64x64 = 4x4 mfma_16x16x32).
// K = 2048, lda = 2048 hardcoded (true for every call in this model).
//   - B staged via global_load_lds from packed weights: fully coalesced.
//   - A reg-staged (coalesced dwordx4) -> ds_write into PADDED k-major LDS
//     (slot stride 130): write & read both bank-conflict-free.
//   - 1-deep pipeline, ONE barrier per K-step: prefetch of tile ks+1 issued
//     right after barrier(ks), drained by barrier(ks+1) -> a full ds_read+MFMA
//     phase of latency hiding. Buffer-reuse separated by one barrier (safe).
//   - XCD-aware bijective block swizzle (all grids have nwg % 8 == 0).
// EPI: 0 -> C bf16 = acc ; 1 -> C fp32 = acc + Sf ; 2 -> C fp32 += acc
//      3 -> C bf16 = silu(Sb) * acc   (SwiGLU fusion; Sb bf16, may alias C)
// ---------------------------------------------------------------------------
template <int EPI>
__global__ __launch_bounds__(256) void mfma_gemm_kernel(
    const __hip_bfloat16* __restrict__ A,
    const __hip_bfloat16* __restrict__ BP,
    const void* __restrict__ S,
    void* __restrict__ Cout,
    int ldc) {
    __shared__ __align__(16) __hip_bfloat16 Asb[2][4160];   // 2 x 520 slots (pad 130/k2)
    __shared__ __align__(16) __hip_bfloat16 Bsb[2][4096];   // 2 x 512 slots linear
    const int tid  = threadIdx.x;
    const int lane = tid & 63;
    const int wave = tid >> 6;
    const int quad = lane >> 4;
    const int l16  = lane & 15;
    // XCD swizzle (bijective: nwg % 8 == 0 for every launch here)
    const int nbx = gridDim.x;
    const int nwg = nbx * gridDim.y;
    int flat = blockIdx.y * nbx + blockIdx.x;
    flat = (flat & 7) * (nwg >> 3) + (flat >> 3);
    const int bxi = flat % nbx;
    const int byi = flat / nbx;
    const int bm = byi * 128;
    const int bn = bxi * 128;
    const int wm = (wave >> 1) * 64;
    const int wn = (wave & 1) * 64;
    // A reg-staging: thread t -> rows (t>>2), (t>>2)+64 ; k-chunk (t&3)*8
    const int ar = tid >> 2;
    const int ac = tid & 3;
    const __hip_bfloat16* gA = A + (size_t)(bm + ar) * DMODEL + ac * 8;
    const __hip_bfloat16* gB = BP + (size_t)bxi * 64 * 4096 + tid * 8;
    const int wslot = ac * 130 + ar;
    f32x4 acc[4][4] = {};
    // prologue: tile 0 in flight
    bf16x8 a0 = *(const bf16x8*)gA;
    bf16x8 a1 = *(const bf16x8*)(gA + (size_t)64 * DMODEL);
    gload_lds16(gB,        &Bsb[0][wave * 512]);
    gload_lds16(gB + 2048, &Bsb[0][2048 + wave * 512]);
    #pragma unroll 2
    for (int ks = 0; ks < 64; ++ks) {
        const int cur = ks & 1;
        bf16x8* Aw = (bf16x8*)Asb[cur];
        Aw[wslot]      = a0;     // waits A-loads only (issued before B gloads)
        Aw[wslot + 64] = a1;
        __syncthreads();         // drains B(ks) gloads, publishes A writes
        if (ks + 1 < 64) {       // prefetch tile ks+1 (lands by barrier ks+1)
            const int kn = (ks + 1) * 32;
            a0 = *(const bf16x8*)(gA + kn);
            a1 = *(const bf16x8*)(gA + (size_t)64 * DMODEL + kn);
            const __hip_bfloat16* gb = gB + (size_t)(ks + 1) * 4096;
            __hip_bfloat16* bd = (__hip_bfloat16*)Bsb[cur ^ 1];
            gload_lds16(gb,        bd + wave * 512);
            gload_lds16(gb + 2048, bd + 2048 + wave * 512);
        }
        const bf16x8* Af = (const bf16x8*)Asb[cur];
        const bf16x8* Bf = (const bf16x8*)Bsb[cur];
        bf16x8 av[4], bv[4];
        #pragma unroll
        for (int t = 0; t < 4; ++t) {
            av[t] = Af[quad * 130 + wm + t * 16 + l16];
            bv[t] = Bf[quad * 128 + wn + t * 16 + l16];
        }
        #pragma unroll
        for (int tm = 0; tm < 4; ++tm)
            #pragma unroll
            for (int tn2 = 0; tn2 < 4; ++tn2)
                acc[tm][tn2] = __builtin_amdgcn_mfma_f32_16x16x32_bf16(
                    av[tm], bv[tn2], acc[tm][tn2], 0, 0, 0);
    }
    // epilogue: C[row = bm+wm+tm*16+quad*4+r][col = bn+wn+tn*16+l16]
    #pragma unroll
    for (int tm = 0; tm < 4; ++tm) {
        #pragma unroll
        for (int tn2 = 0; tn2 < 4; ++tn2) {
            const int col = bn + wn + tn2 * 16 + l16;
            #pragma unroll
            for (int r = 0; r < 4; ++r) {
                const int row = bm + wm + tm * 16 + quad * 4 + r;
                const size_t off = (size_t)row * ldc + col;
                const float vv = acc[tm][tn2][r];
                if (EPI == 0)      ((__hip_bfloat16*)Cout)[off] = __float2bfloat16(vv);
                else if (EPI == 1) ((float*)Cout)[off] = vv + ((const float*)S)[off];
                else if (EPI == 2) ((float*)Cout)[off] += vv;
                else {
                    const float g = __bfloat162float(((const __hip_bfloat16*)S)[off]);
                    ((__hip_bfloat16*)Cout)[off] =
                        __float2bfloat16(g / (1.f + __expf(-g)) * vv);
                }
            }
        }
    }
}

// ---------------------------------------------------------------------------
// RMSNorm fp32 in -> bf16 out. One block per token row.
// ---------------------------------------------------------------------------
__global__ __launch_bounds__(256) void rmsnorm_bf16_kernel(const float* __restrict__ x,
                                                           const float* __restrict__ w,
                                                           __hip_bfloat16* __restrict__ y) {
    const int row = blockIdx.x;
    const float* xr = x + (size_t)row * DMODEL;
    __hip_bfloat16* yr = y + (size_t)row * DMODEL;
    const int t = threadIdx.x;
    float4 v0 = ((const float4*)xr)[t];
    float4 v1 = ((const float4*)xr)[t + 256];
    float ss = v0.x*v0.x + v0.y*v0.y + v0.z*v0.z + v0.w*v0.w
             + v1.x*v1.x + v1.y*v1.y + v1.z*v1.z + v1.w*v1.w;
    #pragma unroll
    for (int off = 32; off; off >>= 1) ss += __shfl_xor(ss, off);
    __shared__ float red[4];
    if ((t & 63) == 0) red[t >> 6] = ss;
    __syncthreads();
    const float rs = rsqrtf((red[0] + red[1] + red[2] + red[3]) * (1.0f / DMODEL) + 1e-5f);
    float4 w0 = ((const float4*)w)[t];
    float4 w1 = ((const float4*)w)[t + 256];
    __hip_bfloat162 a, b, c, d;
    a.x = __float2bfloat16(v0.x * rs * w0.x); a.y = __float2bfloat16(v0.y * rs * w0.y);
    b.x = __float2bfloat16(v0.z * rs * w0.z); b.y = __float2bfloat16(v0.w * rs * w0.w);
    c.x = __float2bfloat16(v1.x * rs * w1.x); c.y = __float2bfloat16(v1.y * rs * w1.y);
    d.x = __float2bfloat16(v1.z * rs * w1.z); d.y = __float2bfloat16(v1.w * rs * w1.w);
    __hip_bfloat162* o0 = (__hip_bfloat162*)&yr[4 * t];
    o0[0] = a; o0[1] = b;
    __hip_bfloat162* o1 = (__hip_bfloat162*)&yr[1024 + 4 * t];
    o1[0] = c; o1[1] = d;
}

// ---------------------------------------------------------------------------
// RoPE in-place on bf16. x: [NT, nh, 64]; pair (i, i+32), angle t*500000^(-i/32)
// ---------------------------------------------------------------------------
__global__ __launch_bounds__(256) void rope_bf16_kernel(__hip_bfloat16* __restrict__ x,
                                                        int nh, int total) {
    const int idx = blockIdx.x * 256 + threadIdx.x;
    if (idx >= total) return;
    const int i = idx & 31;
    const int head_tok = idx >> 5;
    const int t = (head_tok / nh) % TSEQ;
    const float f = (float)t * powf(500000.0f, -(float)i * (1.0f / 32.0f));
    const float c = cosf(f), s = sinf(f);
    __hip_bfloat16* p = x + (size_t)head_tok * HDIM + i;
    const float x1 = __bfloat162float(p[0]), x2 = __bfloat162float(p[32]);
    p[0]  = __float2bfloat16(x1 * c - x2 * s);
    p[32] = __float2bfloat16(x2 * c + x1 * s);
}

// ---------------------------------------------------------------------------
// GQA causal attention (bf16 in/out, fp32 math). One block per (b, kvh).
// Dot products use 4-way split accumulators to cut the serial FMA chain 4x.
// ---------------------------------------------------------------------------
__global__ __launch_bounds__(256) void attn_kernel(const __hip_bfloat16* __restrict__ q,
                                                   const __hip_bfloat16* __restrict__ k,
                                                   const __hip_bfloat16* __restrict__ v,
                                                   __hip_bfloat16* __restrict__ o) {
    __shared__ float ks[TSEQ][65];
    __shared__ float qs[4][64];
    __shared__ float ps[4][TSEQ];
    const int b = blockIdx.x >> 3;
    const int kvh = blockIdx.x & 7;
    const int tid = threadIdx.x, wave = tid >> 6, lane = tid & 63;

    for (int idx = tid; idx < TSEQ * HDIM; idx += 256) {
        int tk = idx >> 6, hd = idx & 63;
        ks[tk][hd] = __bfloat162float(k[((size_t)(b * TSEQ + tk) * NKVH + kvh) * HDIM + hd]);
    }
    __syncthreads();

    const __hip_bfloat16* vb = v + ((size_t)(b * TSEQ) * NKVH + kvh) * HDIM + lane;
    for (int r = wave; r < 4 * TSEQ; r += 4) {
        const int hl = r / TSEQ;
        const int tq = r - hl * TSEQ;
        const int h = kvh * 4 + hl;
        qs[wave][lane] = __bfloat162float(q[((size_t)(b * TSEQ + tq) * NH + h) * HDIM + lane]) * 0.125f;
        float sreg[4];
        float m = -INFINITY;
        #pragma unroll
        for (int c = 0; c < 4; ++c) {
            const int tk = c * 64 + lane;
            float sc = -INFINITY;
            if (tk <= tq) {
                float p0 = 0.f, p1 = 0.f, p2 = 0.f, p3 = 0.f;
                #pragma unroll
                for (int hd = 0; hd < 64; hd += 4) {
                    p0 += qs[wave][hd]     * ks[tk][hd];
                    p1 += qs[wave][hd + 1] * ks[tk][hd + 1];
                    p2 += qs[wave][hd + 2] * ks[tk][hd + 2];
                    p3 += qs[wave][hd + 3] * ks[tk][hd + 3];
                }
                sc = (p0 + p1) + (p2 + p3);
            }
            sreg[c] = sc;
            m = fmaxf(m, sc);
        }
        #pragma unroll
        for (int off = 32; off; off >>= 1) m = fmaxf(m, __shfl_xor(m, off));
        float l = 0.f;
        #pragma unroll
        for (int c = 0; c < 4; ++c) {
            const int tk = c * 64 + lane;
            const float p = __expf(sreg[c] - m);
            if (tk < TSEQ) ps[wave][tk] = p;
            l += p;
        }
        #pragma unroll
        for (int off = 32; off; off >>= 1) l += __shfl_xor(l, off);
        float a0 = 0.f, a1 = 0.f, a2 = 0.f, a3 = 0.f;
        int tk = 0;
        for (; tk + 4 <= tq + 1; tk += 4) {
            a0 += ps[wave][tk]     * __bfloat162float(vb[(size_t)(tk)     * 512]);
            a1 += ps[wave][tk + 1] * __bfloat162float(vb[(size_t)(tk + 1) * 512]);
            a2 += ps[wave][tk + 2] * __bfloat162float(vb[(size_t)(tk + 2) * 512]);
            a3 += ps[wave][tk + 3] * __bfloat162float(vb[(size_t)(tk + 3) * 512]);
        }
        for (; tk <= tq; ++tk)
            a0 += ps[wave][tk] * __bfloat162float(vb[(size_t)tk * 512]);
        const float acc = (a0 + a1) + (a2 + a3);
        o[((size_t)(b * TSEQ + tq) * NH + h) * HDIM + lane] = __float2bfloat16(acc / l);
    }
}

// ---------------------------------------------------------------------------
// Head projection (fp32, precision-critical path): zp = (x2 * w_norm) @ Wp.
// The final rmsnorm's per-row rsqrt cancels under the subsequent normalize.
// ---------------------------------------------------------------------------
__global__ __launch_bounds__(256) void sgemm_head_kernel(const float* __restrict__ A,
                                                         const float* __restrict__ wn_,
                                                         const float* __restrict__ B,
                                                         float* __restrict__ C,
                                                         int K, int lda, int ldb, int ldc) {
    __shared__ float As[16][68];
    __shared__ float Bs[16][64];
    const int tid = threadIdx.x;
    const int tx = tid & 15, ty = tid >> 4;
    const int bm = blockIdx.y * 64;
    const int bn = blockIdx.x * 64;
    const int ar = tid >> 2, ac = (tid & 3) * 4;
    const int br = tid >> 4, bc = (tid & 15) * 4;
    float acc[4][4] = {};
    for (int k0 = 0; k0 < K; k0 += 16) {
        float4 av = *(const float4*)&A[(size_t)(bm + ar) * lda + k0 + ac];
        float4 wv = *(const float4*)&wn_[k0 + ac];
        float4 bv = *(const float4*)&B[(size_t)(k0 + br) * ldb + bn + bc];
        av.x *= wv.x; av.y *= wv.y; av.z *= wv.z; av.w *= wv.w;
        __syncthreads();
        As[ac + 0][ar] = av.x; As[ac + 1][ar] = av.y;
        As[ac + 2][ar] = av.z; As[ac + 3][ar] = av.w;
        *(float4*)&Bs[br][bc] = bv;
        __syncthreads();
        #pragma unroll
        for (int kk = 0; kk < 16; ++kk) {
            float4 a = *(const float4*)&As[kk][ty * 4];
            float4 b = *(const float4*)&Bs[kk][tx * 4];
            acc[0][0] += a.x * b.x; acc[0][1] += a.x * b.y; acc[0][2] += a.x * b.z; acc[0][3] += a.x * b.w;
            acc[1][0] += a.y * b.x; acc[1][1] += a.y * b.y; acc[1][2] += a.y * b.z; acc[1][3] += a.y * b.w;
            acc[2][0] += a.z * b.x; acc[2][1] += a.z * b.y; acc[2][2] += a.z * b.z; acc[2][3] += a.z * b.w;
            acc[3][0] += a.w * b.x; acc[3][1] += a.w * b.y; acc[3][2] += a.w * b.z; acc[3][3] += a.w * b.w;
        }
    }
    #pragma unroll
    for (int i = 0; i < 4; ++i) {
        const size_t off = (size_t)(bm + ty * 4 + i) * ldc + bn + tx * 4;
        *(float4*)&C[off] = make_float4(acc[i][0], acc[i][1], acc[i][2], acc[i][3]);
    }
}

// ---------------------------------------------------------------------------
// zq = normalize(query @ Wqh) : 64 blocks x 128 threads (fp32)
// ---------------------------------------------------------------------------
__global__ __launch_bounds__(128) void zq_kernel(const float* __restrict__ query,
                                                 const float* __restrict__ Wqh,
                                                 float* __restrict__ zq) {
    const int b = blockIdx.x, j = threadIdx.x;
    const float* qr = query + (size_t)b * QDIMC;
    float acc = 0.f;
    for (int kk = 0; kk < QDIMC; ++kk) acc += qr[kk] * Wqh[(size_t)kk * PDIMC + j];
    float ss = acc * acc;
    #pragma unroll
    for (int off = 32; off; off >>= 1) ss += __shfl_xor(ss, off);
    __shared__ float red[2];
    if ((j & 63) == 0) red[j >> 6] = ss;
    __syncthreads();
    zq[(size_t)b * PDIMC + j] = acc * rsqrtf(red[0] + red[1]);
}

// ---------------------------------------------------------------------------
// out[b,t] = dot(normalize(zp[b,t]), zq[b]) * scale + bias : 1 block/token
// ---------------------------------------------------------------------------
__global__ __launch_bounds__(128) void head_kernel(const float* __restrict__ zp,
                                                   const float* __restrict__ zq,
                                                   const float* __restrict__ scale,
                                                   const float* __restrict__ bias,
                                                   float* __restrict__ out) {
    const int row = blockIdx.x;
    const int b = row / TSEQ;
    const int j = threadIdx.x;
    const float zpv = zp[(size_t)row * PDIMC + j];
    const float zqv = zq[(size_t)b * PDIMC + j];
    float ss = zpv * zpv, dd = zpv * zqv;
    #pragma unroll
    for (int off = 32; off; off >>= 1) { ss += __shfl_xor(ss, off); dd += __shfl_xor(dd, off); }
    __shared__ float rs2[2], rd2[2];
    if ((j & 63) == 0) { rs2[j >> 6] = ss; rd2[j >> 6] = dd; }
    __syncthreads();
    if (j == 0)
        out[row] = (rd2[0] + rd2[1]) * rsqrtf(rs2[0] + rs2[1]) * scale[0] + bias[0];
}

// ---------------------------------------------------------------------------
extern "C" void kernel_launch(void* const* d_in, const int* in_sizes, int n_in,
                              void* d_out, int out_size, void* d_ws, size_t ws_size,
                              hipStream_t stream) {
    const float* x       = (const float*)d_in[0];
    const float* query   = (const float*)d_in[1];
    const float* Wq      = (const float*)d_in[2];
    const float* Wk      = (const float*)d_in[3];
    const float* Wv      = (const float*)d_in[4];
    const float* Wo      = (const float*)d_in[5];
    const float* Wgate   = (const float*)d_in[6];
    const float* Wup     = (const float*)d_in[7];
    const float* Wdown   = (const float*)d_in[8];
    const float* w_ln_in = (const float*)d_in[9];
    const float* w_ln_po = (const float*)d_in[10];
    const float* w_norm  = (const float*)d_in[11];
    const float* Wp      = (const float*)d_in[12];
    const float* Wqh     = (const float*)d_in[13];
    const float* scale   = (const float*)d_in[14];
    const float* bias    = (const float*)d_in[15];
    float* out = (float*)d_out;

    // Workspace: 243.8 MB total (< proven 245 MB budget)
    char* ws = (char*)d_ws;
    __hip_bfloat16* R1 = (__hip_bfloat16*)ws;                 // 51.38MB: h -> o -> h2
    __hip_bfloat16* R2 = (__hip_bfloat16*)(ws + 51380224);    // 51.38MB: q -> g/act -> zp,zq
    __hip_bfloat16* R3 = (__hip_bfloat16*)(ws + 102760448);   // 12.85MB: k
    __hip_bfloat16* R4 = (__hip_bfloat16*)(ws + 115605504);   // 12.85MB: v
    float*          x1 = (float*)(ws + 128450560);            // 102.76MB: fp32 residual
    __hip_bfloat16* packW = (__hip_bfloat16*)(ws + 231211008); // 12.58MB region (use <=8.4MB)
    float* zp = (float*)(ws + 51380224);                // over R2 (act dead at head time)
    float* zq = zp + (size_t)NT * PDIMC;

    // --- self-attn sublayer ---
    rmsnorm_bf16_kernel<<<NT, 256, 0, stream>>>(x, w_ln_in, R1);
    pack_cast_kernel<<<2048, 256, 0, stream>>>(Wq, packW, 2048);
    mfma_gemm_kernel<0><<<dim3(16, 98), 256, 0, stream>>>(R1, packW, nullptr, R2, 2048);
    pack_cast_kernel<<<512, 256, 0, stream>>>(Wk, packW, 512);
    mfma_gemm_kernel<0><<<dim3(4, 98), 256, 0, stream>>>(R1, packW, nullptr, R3, 512);
    pack_cast_kernel<<<512, 256, 0, stream>>>(Wv, packW, 512);
    mfma_gemm_kernel<0><<<dim3(4, 98), 256, 0, stream>>>(R1, packW, nullptr, R4, 512);
    rope_bf16_kernel<<<(NT * NH * 32) / 256, 256, 0, stream>>>(R2, NH, NT * NH * 32);
    rope_bf16_kernel<<<(NT * NKVH * 32) / 256, 256, 0, stream>>>(R3, NKVH, NT * NKVH * 32);
    attn_kernel<<<BATCH * NKVH, 256, 0, stream>>>(R2, R3, R4, R1);   // o -> R1 (h dead)
    pack_cast_kernel<<<2048, 256, 0, stream>>>(Wo, packW, 2048);
    mfma_gemm_kernel<1><<<dim3(16, 98), 256, 0, stream>>>(R1, packW, x, x1, 2048);
    // --- MLP sublayer (SwiGLU), I chunked by 2048, JIT weight pack ---
    rmsnorm_bf16_kernel<<<NT, 256, 0, stream>>>(x1, w_ln_po, R1);    // h2 -> R1
    for (int c = 0; c < 4; ++c) {
        pack_cast_kernel<<<2048, 256, 0, stream>>>(Wgate + (size_t)c * 2048, packW, 8192);
        mfma_gemm_kernel<0><<<dim3(16, 98), 256, 0, stream>>>(R1, packW, nullptr, R2, 2048);
        pack_cast_kernel<<<2048, 256, 0, stream>>>(Wup + (size_t)c * 2048, packW, 8192);
        mfma_gemm_kernel<3><<<dim3(16, 98), 256, 0, stream>>>(R1, packW, R2, R2, 2048);
        pack_cast_kernel<<<2048, 256, 0, stream>>>(Wdown + (size_t)c * 2048 * DMODEL, packW, 2048);
        mfma_gemm_kernel<2><<<dim3(16, 98), 256, 0, stream>>>(R2, packW, nullptr, x1, 2048);
    }
    // --- head (fp32; final rmsnorm's row scale cancels under normalize) ---
    sgemm_head_kernel<<<dim3(2, 196), 256, 0, stream>>>(x1, w_norm, Wp, zp, 2048, 2048, PDIMC, PDIMC);
    zq_kernel<<<BATCH, 128, 0, stream>>>(query, Wqh, zq);
    head_kernel<<<NT, 128, 0, stream>>>(zp, zq, scale, bias, out);
}

// Round 3
// 3104.512 us; speedup vs baseline: 1.4966x; 1.4966x over previous
//
#include <hip/hip_runtime.h>
#include <hip/hip_bf16.h>
#include <cstddef>

// Problem constants
#define NT     12544   // B*T tokens
#define BATCH  64
#define TSEQ   196
#define DMODEL 2048
#define NH     32
#define NKVH   8
#define HDIM   64
#define IMLP   8192
#define QDIMC  512
#define PDIMC  128

typedef __bf16 bf16x8 __attribute__((ext_vector_type(8)));
typedef float f32x4 __attribute__((ext_vector_type(4)));

// ---------------------------------------------------------------------------
// async global->LDS, 16B per lane (dest = wave-uniform base + lane*16)
// ---------------------------------------------------------------------------
__device__ __forceinline__ void gload_lds16(const void* g, void* l) {
    __builtin_amdgcn_global_load_lds(
        (__attribute__((address_space(1))) void*)g,
        (__attribute__((address_space(3))) void*)l, 16, 0, 0);
}

// ---------------------------------------------------------------------------
// Weight pre-pack: W[K=2048, N] fp32 (row stride ldw) -> tile-packed bf16.
// 128x32 tile = 512 16B-slots; slot S(m,kc) = m*4 + ((kc + (m>>2)) & 3)
// holds W[ks*32 + kc*8 .. +7][tn*128 + m]. The XOR-ish swizzle makes the
// GEMM's ds_read_b128 fragment reads 2-way bank-conflict-free (free), while
// global_load_lds staging stays linear (lane t -> slot t).
// ---------------------------------------------------------------------------
__global__ __launch_bounds__(256) void pack_cast_kernel(const float* __restrict__ W,
                                                        __hip_bfloat16* __restrict__ P,
                                                        int ldw) {
    const int bid  = blockIdx.x;
    const int tile = bid >> 1;
    const int tn   = tile >> 6;          // K fixed at 2048 -> KS = 64
    const int ks   = tile & 63;
    const int within = ((bid & 1) << 8) | threadIdx.x;   // 0..511
    const int k2 = within >> 7, m = within & 127;        // k2 0..3, m 0..127
    const float* src = W + (size_t)(ks * 32 + k2 * 8) * ldw + tn * 128 + m;
    union { bf16x8 v; __hip_bfloat16 h[8]; } u;
    #pragma unroll
    for (int kin = 0; kin < 8; ++kin)
        u.h[kin] = __float2bfloat16(src[(size_t)kin * ldw]);
    const int slot = m * 4 + ((k2 + (m >> 2)) & 3);
    *(bf16x8*)(P + (size_t)tile * 4096 + slot * 8) = u.v;
}

// ---------------------------------------------------------------------------
// bf16 MFMA GEMM: C[M,N] = A[M,2048] @ B (B tile-packed). 128x128 tile, BK=32,
// 256 thr / 4 waves. K = 2048, lda = 2048 hardcoded.
//   - 3-slot LDS ring, depth-2 prefetch, raw s_barrier + COUNTED vmcnt (T4):
//     tile t computed from slot t%3 while t+1,t+2 in flight. vmcnt(4) at iter
//     top forces tile t landed (FIFO counter, m135); loads stay in flight
//     ACROSS barriers. Ledger: stage(t+2) issued after barrier(t) => all
//     reads of the tile that occupied slot (t+2)%3 completed (per-wave
//     lgkmcnt waits precede the MFMAs that precede the barrier).
//   - Swizzled 16B-slot layout S(row,kc) = row*4 + ((kc+(row>>2))&3):
//     frag ds_read_b128 = 2 lanes/bank-column (free, m136). Staging stays
//     linear: lane t writes slot t, so A's per-lane SOURCE k-chunk is
//     kc = ((t&3)-(t>>4))&3 (same 64B segment per 4-lane group -> coalesced).
//   - s_setprio(1) around MFMA cluster (T5; counted-vmcnt phase structure).
// EPI: 0 -> C bf16 = acc ; 1 -> C fp32 = acc + Sf ; 2 -> C fp32 += acc
//      3 -> C bf16 = silu(Sb) * acc   (SwiGLU fusion; Sb bf16, may alias C)
// ---------------------------------------------------------------------------
template <int EPI>
__global__ __launch_bounds__(256) void mfma_gemm_kernel(
    const __hip_bfloat16* __restrict__ A,
    const __hip_bfloat16* __restrict__ BP,
    const void* __restrict__ S,
    void* __restrict__ Cout,
    int ldc) {
    __shared__ __align__(16) __hip_bfloat16 Asb[3][4096];   // 3 x 8 KB
    __shared__ __align__(16) __hip_bfloat16 Bsb[3][4096];   // 3 x 8 KB
    const int tid  = threadIdx.x;
    const int lane = tid & 63;
    const int wave = tid >> 6;
    const int quad = lane >> 4;
    const int l16  = lane & 15;
    // XCD swizzle (bijective: nwg % 8 == 0 for every launch here)
    const int nbx = gridDim.x;
    const int nwg = nbx * gridDim.y;
    int flat = blockIdx.y * nbx + blockIdx.x;
    flat = (flat & 7) * (nwg >> 3) + (flat >> 3);
    const int bxi = flat % nbx;
    const int byi = flat / nbx;
    const int bm = byi * 128;
    const int bn = bxi * 128;
    const int wm = (wave >> 1) * 64;
    const int wn = (wave & 1) * 64;
    // A staging: lane t -> slot t (per half): row = t>>2, kc = ((t&3)-(t>>4))&3
    const int kcA = ((tid & 3) - (tid >> 4)) & 3;
    const __hip_bfloat16* pA0 = A + (size_t)(bm + (tid >> 2)) * 2048 + kcA * 8;
    const __hip_bfloat16* pA1 = pA0 + (size_t)64 * 2048;
    const __hip_bfloat16* pB  = BP + (size_t)bxi * 262144 + tid * 8;
    const int wb = wave * 512;   // wave-uniform LDS dest offset (elems)
    const int sw = (quad + (l16 >> 2)) & 3;   // read-side swizzle

    f32x4 acc[4][4] = {};
    // prologue: tiles 0,1 in flight
    {
        gload_lds16(pA0,         &Asb[0][wb]);
        gload_lds16(pA1,         &Asb[0][2048 + wb]);
        gload_lds16(pB,          &Bsb[0][wb]);
        gload_lds16(pB + 2048,   &Bsb[0][2048 + wb]);
        gload_lds16(pA0 + 32,    &Asb[1][wb]);
        gload_lds16(pA1 + 32,    &Asb[1][2048 + wb]);
        gload_lds16(pB + 4096,   &Bsb[1][wb]);
        gload_lds16(pB + 6144,   &Bsb[1][2048 + wb]);
    }
    int slot = 0;
    for (int t = 0; t < 64; ++t) {
        if (t < 63) asm volatile("s_waitcnt vmcnt(4)" ::: "memory");
        else        asm volatile("s_waitcnt vmcnt(0)" ::: "memory");
        __builtin_amdgcn_s_barrier();
        __builtin_amdgcn_sched_barrier(0);
        if (t + 2 < 64) {
            int s2 = slot + 2; if (s2 >= 3) s2 -= 3;
            const int kn = (t + 2) * 32;
            const __hip_bfloat16* b2 = pB + (size_t)(t + 2) * 4096;
            gload_lds16(pA0 + kn,   &Asb[s2][wb]);
            gload_lds16(pA1 + kn,   &Asb[s2][2048 + wb]);
            gload_lds16(b2,         &Bsb[s2][wb]);
            gload_lds16(b2 + 2048,  &Bsb[s2][2048 + wb]);
        }
        const bf16x8* Af = (const bf16x8*)Asb[slot];
        const bf16x8* Bf = (const bf16x8*)Bsb[slot];
        bf16x8 av[4], bv[4];
        #pragma unroll
        for (int i = 0; i < 4; ++i) {
            av[i] = Af[(wm + i * 16 + l16) * 4 + sw];
            bv[i] = Bf[(wn + i * 16 + l16) * 4 + sw];
        }
        __builtin_amdgcn_s_setprio(1);
        #pragma unroll
        for (int tm = 0; tm < 4; ++tm)
            #pragma unroll
            for (int tn2 = 0; tn2 < 4; ++tn2)
                acc[tm][tn2] = __builtin_amdgcn_mfma_f32_16x16x32_bf16(
                    av[tm], bv[tn2], acc[tm][tn2], 0, 0, 0);
        __builtin_amdgcn_s_setprio(0);
        ++slot; if (slot == 3) slot = 0;
    }
    // epilogue: C[row = bm+wm+tm*16+quad*4+r][col = bn+wn+tn*16+l16]
    #pragma unroll
    for (int tm = 0; tm < 4; ++tm) {
        #pragma unroll
        for (int tn2 = 0; tn2 < 4; ++tn2) {
            const int col = bn + wn + tn2 * 16 + l16;
            #pragma unroll
            for (int r = 0; r < 4; ++r) {
                const int row = bm + wm + tm * 16 + quad * 4 + r;
                const size_t off = (size_t)row * ldc + col;
                const float vv = acc[tm][tn2][r];
                if (EPI == 0)      ((__hip_bfloat16*)Cout)[off] = __float2bfloat16(vv);
                else if (EPI == 1) ((float*)Cout)[off] = vv + ((const float*)S)[off];
                else if (EPI == 2) ((float*)Cout)[off] += vv;
                else {
                    const float g = __bfloat162float(((const __hip_bfloat16*)S)[off]);
                    ((__hip_bfloat16*)Cout)[off] =
                        __float2bfloat16(g / (1.f + __expf(-g)) * vv);
                }
            }
        }
    }
}

// ---------------------------------------------------------------------------
// RMSNorm fp32 in -> bf16 out. One block per token row.
// ---------------------------------------------------------------------------
__global__ __launch_bounds__(256) void rmsnorm_bf16_kernel(const float* __restrict__ x,
                                                           const float* __restrict__ w,
                                                           __hip_bfloat16* __restrict__ y) {
    const int row = blockIdx.x;
    const float* xr = x + (size_t)row * DMODEL;
    __hip_bfloat16* yr = y + (size_t)row * DMODEL;
    const int t = threadIdx.x;
    float4 v0 = ((const float4*)xr)[t];
    float4 v1 = ((const float4*)xr)[t + 256];
    float ss = v0.x*v0.x + v0.y*v0.y + v0.z*v0.z + v0.w*v0.w
             + v1.x*v1.x + v1.y*v1.y + v1.z*v1.z + v1.w*v1.w;
    #pragma unroll
    for (int off = 32; off; off >>= 1) ss += __shfl_xor(ss, off);
    __shared__ float red[4];
    if ((t & 63) == 0) red[t >> 6] = ss;
    __syncthreads();
    const float rs = rsqrtf((red[0] + red[1] + red[2] + red[3]) * (1.0f / DMODEL) + 1e-5f);
    float4 w0 = ((const float4*)w)[t];
    float4 w1 = ((const float4*)w)[t + 256];
    __hip_bfloat162 a, b, c, d;
    a.x = __float2bfloat16(v0.x * rs * w0.x); a.y = __float2bfloat16(v0.y * rs * w0.y);
    b.x = __float2bfloat16(v0.z * rs * w0.z); b.y = __float2bfloat16(v0.w * rs * w0.w);
    c.x = __float2bfloat16(v1.x * rs * w1.x); c.y = __float2bfloat16(v1.y * rs * w1.y);
    d.x = __float2bfloat16(v1.z * rs * w1.z); d.y = __float2bfloat16(v1.w * rs * w1.w);
    __hip_bfloat162* o0 = (__hip_bfloat162*)&yr[4 * t];
    o0[0] = a; o0[1] = b;
    __hip_bfloat162* o1 = (__hip_bfloat162*)&yr[1024 + 4 * t];
    o1[0] = c; o1[1] = d;
}

// ---------------------------------------------------------------------------
// RoPE in-place on bf16. x: [NT, nh, 64]; pair (i, i+32), angle t*500000^(-i/32)
// ---------------------------------------------------------------------------
__global__ __launch_bounds__(256) void rope_bf16_kernel(__hip_bfloat16* __restrict__ x,
                                                        int nh, int total) {
    const int idx = blockIdx.x * 256 + threadIdx.x;
    if (idx >= total) return;
    const int i = idx & 31;
    const int head_tok = idx >> 5;
    const int t = (head_tok / nh) % TSEQ;
    const float f = (float)t * powf(500000.0f, -(float)i * (1.0f / 32.0f));
    const float c = cosf(f), s = sinf(f);
    __hip_bfloat16* p = x + (size_t)head_tok * HDIM + i;
    const float x1 = __bfloat162float(p[0]), x2 = __bfloat162float(p[32]);
    p[0]  = __float2bfloat16(x1 * c - x2 * s);
    p[32] = __float2bfloat16(x2 * c + x1 * s);
}

// ---------------------------------------------------------------------------
// MFMA GQA causal attention. One block per (b, kvh); 8 waves (512 thr).
// Wave w handles head kvh*4 + (w&3), row-tiles rt = (w>>2), (w>>2)+2, ...
// K LDS: [tk][64] with 16B-chunk swizzle (kc + (tk&7))&7 -> QK^T frag reads
// are 2-way bank-conflict-free. V^T and per-wave P buffers as before.
// ---------------------------------------------------------------------------
__global__ __launch_bounds__(512) void attn_mfma_kernel(const __hip_bfloat16* __restrict__ q,
                                                        const __hip_bfloat16* __restrict__ k,
                                                        const __hip_bfloat16* __restrict__ v,
                                                        __hip_bfloat16* __restrict__ o) {
    __shared__ __align__(16) __hip_bfloat16 Kl[208 * 64];    // swizzled (26.6 KB)
    __shared__ __align__(16) __hip_bfloat16 Vt[64 * 232];    // [hd][232] (29.7 KB)
    __shared__ __align__(16) __hip_bfloat16 Ps[8][16 * 232]; // per-wave P (59.4 KB)
    const int b = blockIdx.x >> 3;
    const int kvh = blockIdx.x & 7;
    const int tid = threadIdx.x, wave = tid >> 6, lane = tid & 63;
    const int quad = lane >> 4, l16 = lane & 15;

    // stage K (swizzled chunks): rows >=196 zeroed
    for (int idx = tid; idx < 208 * 8; idx += 512) {
        const int tk = idx >> 3, c = idx & 7;
        bf16x8 val = {};
        if (tk < 196) val = *(const bf16x8*)&k[((size_t)(b * 196 + tk) * 8 + kvh) * 64 + c * 8];
        *(bf16x8*)&Kl[tk * 64 + ((c + (tk & 7)) & 7) * 8] = val;
    }
    // stage V^T: cols(tk) >=196 zeroed up to 224 (PV reads tk < 224)
    for (int idx = tid; idx < 224 * 64; idx += 512) {
        const int tk = idx >> 6, hd = idx & 63;
        float val = 0.f;
        if (tk < 196) val = __bfloat162float(v[((size_t)(b * 196 + tk) * 8 + kvh) * 64 + hd]);
        Vt[hd * 232 + tk] = __float2bfloat16(val);
    }
    __syncthreads();

    const int h = kvh * 4 + (wave & 3);
    const int swk0 = l16 & 7;                 // tk & 7 == l16 & 7 (ct*16 = 0 mod 8)
    __hip_bfloat16* pw = &Ps[wave][0];
    for (int rt = wave >> 2; rt < 13; rt += 2) {
        // Q A-frag (direct from global; rows >=196 read garbage, never stored)
        const size_t qoff = ((size_t)(b * 196 + rt * 16 + l16) * 32 + h) * 64 + quad * 8;
        const bf16x8 qa0 = *(const bf16x8*)&q[qoff];
        const bf16x8 qa1 = *(const bf16x8*)&q[qoff + 32];
        // S = Q K^T for col-tiles ct <= rt
        f32x4 sf[13];
        #pragma unroll
        for (int ct = 0; ct < 13; ++ct) {
            if (ct <= rt) {
                const int tkr = ct * 16 + l16;
                const bf16x8 k0 = *(const bf16x8*)&Kl[tkr * 64 + ((quad + swk0) & 7) * 8];
                const bf16x8 k1 = *(const bf16x8*)&Kl[tkr * 64 + ((quad + 4 + swk0) & 7) * 8];
                f32x4 s = {};
                s = __builtin_amdgcn_mfma_f32_16x16x32_bf16(qa0, k0, s, 0, 0, 0);
                s = __builtin_amdgcn_mfma_f32_16x16x32_bf16(qa1, k1, s, 0, 0, 0);
                sf[ct] = s;
            }
        }
        // scale + causal mask + row max (rows = rt*16 + quad*4 + r, col = ct*16 + l16)
        float mrow[4] = {-INFINITY, -INFINITY, -INFINITY, -INFINITY};
        #pragma unroll
        for (int ct = 0; ct < 13; ++ct) {
            if (ct <= rt) {
                #pragma unroll
                for (int r = 0; r < 4; ++r) {
                    const int row = rt * 16 + quad * 4 + r;
                    const int col = ct * 16 + l16;
                    float s = sf[ct][r] * 0.125f;
                    if (col > row) s = -INFINITY;
                    sf[ct][r] = s;
                    mrow[r] = fmaxf(mrow[r], s);
                }
            }
        }
        #pragma unroll
        for (int r = 0; r < 4; ++r) {
            float m = mrow[r];
            m = fmaxf(m, __shfl_xor(m, 1));
            m = fmaxf(m, __shfl_xor(m, 2));
            m = fmaxf(m, __shfl_xor(m, 4));
            m = fmaxf(m, __shfl_xor(m, 8));
            mrow[r] = m;
        }
        // exp + row sum
        float ls[4] = {0.f, 0.f, 0.f, 0.f};
        #pragma unroll
        for (int ct = 0; ct < 13; ++ct) {
            if (ct <= rt) {
                #pragma unroll
                for (int r = 0; r < 4; ++r) {
                    const float p = __expf(sf[ct][r] - mrow[r]);
                    sf[ct][r] = p;
                    ls[r] += p;
                }
            }
        }
        #pragma unroll
        for (int r = 0; r < 4; ++r) {
            float s = ls[r];
            s += __shfl_xor(s, 1);
            s += __shfl_xor(s, 2);
            s += __shfl_xor(s, 4);
            s += __shfl_xor(s, 8);
            ls[r] = s;
        }
        // P -> bf16 -> per-wave LDS (transpose to A-frag order)
        #pragma unroll
        for (int ct = 0; ct < 13; ++ct) {
            if (ct <= rt) {
                #pragma unroll
                for (int r = 0; r < 4; ++r)
                    pw[(quad * 4 + r) * 232 + ct * 16 + l16] = __float2bfloat16(sf[ct][r]);
            }
        }
        if (!(rt & 1)) {    // zero-fill up to the 32-k-tile boundary
            const int ct = rt + 1;
            #pragma unroll
            for (int r = 0; r < 4; ++r)
                pw[(quad * 4 + r) * 232 + ct * 16 + l16] = __float2bfloat16(0.f);
        }
        asm volatile("s_waitcnt lgkmcnt(0)" ::: "memory");
        // O = P V  (A = P[l16][tk], B = Vt[hd][tk])
        const int nkt = (rt >> 1) + 1;
        f32x4 of[4] = {};
        #pragma unroll
        for (int ktv = 0; ktv < 7; ++ktv) {
            if (ktv < nkt) {
                const bf16x8 pa = *(const bf16x8*)&pw[l16 * 232 + ktv * 32 + quad * 8];
                #pragma unroll
                for (int co = 0; co < 4; ++co) {
                    const bf16x8 vf = *(const bf16x8*)&Vt[(co * 16 + l16) * 232 + ktv * 32 + quad * 8];
                    of[co] = __builtin_amdgcn_mfma_f32_16x16x32_bf16(pa, vf, of[co], 0, 0, 0);
                }
            }
        }
        // store (C: col = hd(l16), row = quad*4 + r)
        #pragma unroll
        for (int r = 0; r < 4; ++r) {
            const int row = rt * 16 + quad * 4 + r;
            if (row < 196) {
                const float inv = 1.f / ls[r];
                #pragma unroll
                for (int co = 0; co < 4; ++co)
                    o[((size_t)(b * 196 + row) * 32 + h) * 64 + co * 16 + l16] =
                        __float2bfloat16(of[co][r] * inv);
            }
        }
    }
}

// ---------------------------------------------------------------------------
// Head projection (fp32, precision-critical path): zp = (x2 * w_norm) @ Wp.
// ---------------------------------------------------------------------------
__global__ __launch_bounds__(256) void sgemm_head_kernel(const float* __restrict__ A,
                                                         const float* __restrict__ wn_,
                                                         const float* __restrict__ B,
                                                         float* __restrict__ C,
                                                         int K, int lda, int ldb, int ldc) {
    __shared__ float As[16][68];
    __shared__ float Bs[16][64];
    const int tid = threadIdx.x;
    const int tx = tid & 15, ty = tid >> 4;
    const int bm = blockIdx.y * 64;
    const int bn = blockIdx.x * 64;
    const int ar = tid >> 2, ac = (tid & 3) * 4;
    const int br = tid >> 4, bc = (tid & 15) * 4;
    float acc[4][4] = {};
    for (int k0 = 0; k0 < K; k0 += 16) {
        float4 av = *(const float4*)&A[(size_t)(bm + ar) * lda + k0 + ac];
        float4 wv = *(const float4*)&wn_[k0 + ac];
        float4 bv = *(const float4*)&B[(size_t)(k0 + br) * ldb + bn + bc];
        av.x *= wv.x; av.y *= wv.y; av.z *= wv.z; av.w *= wv.w;
        __syncthreads();
        As[ac + 0][ar] = av.x; As[ac + 1][ar] = av.y;
        As[ac + 2][ar] = av.z; As[ac + 3][ar] = av.w;
        *(float4*)&Bs[br][bc] = bv;
        __syncthreads();
        #pragma unroll
        for (int kk = 0; kk < 16; ++kk) {
            float4 a = *(const float4*)&As[kk][ty * 4];
            float4 b = *(const float4*)&Bs[kk][tx * 4];
            acc[0][0] += a.x * b.x; acc[0][1] += a.x * b.y; acc[0][2] += a.x * b.z; acc[0][3] += a.x * b.w;
            acc[1][0] += a.y * b.x; acc[1][1] += a.y * b.y; acc[1][2] += a.y * b.z; acc[1][3] += a.y * b.w;
            acc[2][0] += a.z * b.x; acc[2][1] += a.z * b.y; acc[2][2] += a.z * b.z; acc[2][3] += a.z * b.w;
            acc[3][0] += a.w * b.x; acc[3][1] += a.w * b.y; acc[3][2] += a.w * b.z; acc[3][3] += a.w * b.w;
        }
    }
    #pragma unroll
    for (int i = 0; i < 4; ++i) {
        const size_t off = (size_t)(bm + ty * 4 + i) * ldc + bn + tx * 4;
        *(float4*)&C[off] = make_float4(acc[i][0], acc[i][1], acc[i][2], acc[i][3]);
    }
}

// ---------------------------------------------------------------------------
// zq = normalize(query @ Wqh) : 64 blocks x 128 threads (fp32)
// ---------------------------------------------------------------------------
__global__ __launch_bounds__(128) void zq_kernel(const float* __restrict__ query,
                                                 const float* __restrict__ Wqh,
                                                 float* __restrict__ zq) {
    const int b = blockIdx.x, j = threadIdx.x;
    const float* qr = query + (size_t)b * QDIMC;
    float acc = 0.f;
    for (int kk = 0; kk < QDIMC; ++kk) acc += qr[kk] * Wqh[(size_t)kk * PDIMC + j];
    float ss = acc * acc;
    #pragma unroll
    for (int off = 32; off; off >>= 1) ss += __shfl_xor(ss, off);
    __shared__ float red[2];
    if ((j & 63) == 0) red[j >> 6] = ss;
    __syncthreads();
    zq[(size_t)b * PDIMC + j] = acc * rsqrtf(red[0] + red[1]);
}

// ---------------------------------------------------------------------------
// out[b,t] = dot(normalize(zp[b,t]), zq[b]) * scale + bias : 1 block/token
// ---------------------------------------------------------------------------
__global__ __launch_bounds__(128) void head_kernel(const float* __restrict__ zp,
                                                   const float* __restrict__ zq,
                                                   const float* __restrict__ scale,
                                                   const float* __restrict__ bias,
                                                   float* __restrict__ out) {
    const int row = blockIdx.x;
    const int b = row / TSEQ;
    const int j = threadIdx.x;
    const float zpv = zp[(size_t)row * PDIMC + j];
    const float zqv = zq[(size_t)b * PDIMC + j];
    float ss = zpv * zpv, dd = zpv * zqv;
    #pragma unroll
    for (int off = 32; off; off >>= 1) { ss += __shfl_xor(ss, off); dd += __shfl_xor(dd, off); }
    __shared__ float rs2[2], rd2[2];
    if ((j & 63) == 0) { rs2[j >> 6] = ss; rd2[j >> 6] = dd; }
    __syncthreads();
    if (j == 0)
        out[row] = (rd2[0] + rd2[1]) * rsqrtf(rs2[0] + rs2[1]) * scale[0] + bias[0];
}

// ---------------------------------------------------------------------------
extern "C" void kernel_launch(void* const* d_in, const int* in_sizes, int n_in,
                              void* d_out, int out_size, void* d_ws, size_t ws_size,
                              hipStream_t stream) {
    const float* x       = (const float*)d_in[0];
    const float* query   = (const float*)d_in[1];
    const float* Wq      = (const float*)d_in[2];
    const float* Wk      = (const float*)d_in[3];
    const float* Wv      = (const float*)d_in[4];
    const float* Wo      = (const float*)d_in[5];
    const float* Wgate   = (const float*)d_in[6];
    const float* Wup     = (const float*)d_in[7];
    const float* Wdown   = (const float*)d_in[8];
    const float* w_ln_in = (const float*)d_in[9];
    const float* w_ln_po = (const float*)d_in[10];
    const float* w_norm  = (const float*)d_in[11];
    const float* Wp      = (const float*)d_in[12];
    const float* Wqh     = (const float*)d_in[13];
    const float* scale   = (const float*)d_in[14];
    const float* bias    = (const float*)d_in[15];
    float* out = (float*)d_out;

    // Workspace: 243.8 MB total (< proven 245 MB budget)
    char* ws = (char*)d_ws;
    __hip_bfloat16* R1 = (__hip_bfloat16*)ws;                 // 51.38MB: h -> o -> h2
    __hip_bfloat16* R2 = (__hip_bfloat16*)(ws + 51380224);    // 51.38MB: q -> g/act -> zp,zq
    __hip_bfloat16* R3 = (__hip_bfloat16*)(ws + 102760448);   // 12.85MB: k
    __hip_bfloat16* R4 = (__hip_bfloat16*)(ws + 115605504);   // 12.85MB: v
    float*          x1 = (float*)(ws + 128450560);            // 102.76MB: fp32 residual
    __hip_bfloat16* packW = (__hip_bfloat16*)(ws + 231211008); // 12.58MB region (use <=8.4MB)
    float* zp = (float*)(ws + 51380224);                // over R2 (act dead at head time)
    float* zq = zp + (size_t)NT * PDIMC;

    // --- self-attn sublayer ---
    rmsnorm_bf16_kernel<<<NT, 256, 0, stream>>>(x, w_ln_in, R1);
    pack_cast_kernel<<<2048, 256, 0, stream>>>(Wq, packW, 2048);
    mfma_gemm_kernel<0><<<dim3(16, 98), 256, 0, stream>>>(R1, packW, nullptr, R2, 2048);
    pack_cast_kernel<<<512, 256, 0, stream>>>(Wk, packW, 512);
    mfma_gemm_kernel<0><<<dim3(4, 98), 256, 0, stream>>>(R1, packW, nullptr, R3, 512);
    pack_cast_kernel<<<512, 256, 0, stream>>>(Wv, packW, 512);
    mfma_gemm_kernel<0><<<dim3(4, 98), 256, 0, stream>>>(R1, packW, nullptr, R4, 512);
    rope_bf16_kernel<<<(NT * NH * 32) / 256, 256, 0, stream>>>(R2, NH, NT * NH * 32);
    rope_bf16_kernel<<<(NT * NKVH * 32) / 256, 256, 0, stream>>>(R3, NKVH, NT * NKVH * 32);
    attn_mfma_kernel<<<BATCH * NKVH, 512, 0, stream>>>(R2, R3, R4, R1); // o -> R1
    pack_cast_kernel<<<2048, 256, 0, stream>>>(Wo, packW, 2048);
    mfma_gemm_kernel<1><<<dim3(16, 98), 256, 0, stream>>>(R1, packW, x, x1, 2048);
    // --- MLP sublayer (SwiGLU), I chunked by 2048, JIT weight pack ---
    rmsnorm_bf16_kernel<<<NT, 256, 0, stream>>>(x1, w_ln_po, R1);    // h2 -> R1
    for (int c = 0; c < 4; ++c) {
        pack_cast_kernel<<<2048, 256, 0, stream>>>(Wgate + (size_t)c * 2048, packW, 8192);
        mfma_gemm_kernel<0><<<dim3(16, 98), 256, 0, stream>>>(R1, packW, nullptr, R2, 2048);
        pack_cast_kernel<<<2048, 256, 0, stream>>>(Wup + (size_t)c * 2048, packW, 8192);
        mfma_gemm_kernel<3><<<dim3(16, 98), 256, 0, stream>>>(R1, packW, R2, R2, 2048);
        pack_cast_kernel<<<2048, 256, 0, stream>>>(Wdown + (size_t)c * 2048 * DMODEL, packW, 2048);
        mfma_gemm_kernel<2><<<dim3(16, 98), 256, 0, stream>>>(R2, packW, nullptr, x1, 2048);
    }
    // --- head (fp32; final rmsnorm's row scale cancels under normalize) ---
    sgemm_head_kernel<<<dim3(2, 196), 256, 0, stream>>>(x1, w_norm, Wp, zp, 2048, 2048, PDIMC, PDIMC);
    zq_kernel<<<BATCH, 128, 0, stream>>>(query, Wqh, zq);
    head_kernel<<<NT, 128, 0, stream>>>(zp, zq, scale, bias, out);
}

// Round 4
// 2975.486 us; speedup vs baseline: 1.5615x; 1.0434x over previous
//
#include <hip/hip_runtime.h>
#include <hip/hip_bf16.h>
#include <cstddef>

// Problem constants
#define NT     12544   // B*T tokens
#define BATCH  64
#define TSEQ   196
#define DMODEL 2048
#define NH     32
#define NKVH   8
#define HDIM   64
#define IMLP   8192
#define QDIMC  512
#define PDIMC  128

typedef __bf16 bf16x8 __attribute__((ext_vector_type(8)));
typedef float f32x4 __attribute__((ext_vector_type(4)));

// ---------------------------------------------------------------------------
// async global->LDS, 16B per lane (dest = wave-uniform base + lane*16)
// ---------------------------------------------------------------------------
__device__ __forceinline__ void gload_lds16(const void* g, void* l) {
    __builtin_amdgcn_global_load_lds(
        (__attribute__((address_space(1))) void*)g,
        (__attribute__((address_space(3))) void*)l, 16, 0, 0);
}

// ---------------------------------------------------------------------------
// Weight pre-pack: W[K=2048, N] fp32 (row stride ldw) -> tile-packed bf16.
// 128x32 tile = 512 16B-slots; slot S(m,kc) = m*4 + ((kc + (m>>2)) & 3)
// holds W[ks*32 + kc*8 .. +7][tn*128 + m]. Swizzle makes the GEMM's
// ds_read_b128 fragment reads 2-way bank-conflict-free while global_load_lds
// staging stays linear (lane t -> slot t).
// ---------------------------------------------------------------------------
__global__ __launch_bounds__(256) void pack_cast_kernel(const float* __restrict__ W,
                                                        __hip_bfloat16* __restrict__ P,
                                                        int ldw) {
    const int bid  = blockIdx.x;
    const int tile = bid >> 1;
    const int tn   = tile >> 6;          // K fixed at 2048 -> KS = 64
    const int ks   = tile & 63;
    const int within = ((bid & 1) << 8) | threadIdx.x;   // 0..511
    const int k2 = within >> 7, m = within & 127;        // k2 0..3, m 0..127
    const float* src = W + (size_t)(ks * 32 + k2 * 8) * ldw + tn * 128 + m;
    union { bf16x8 v; __hip_bfloat16 h[8]; } u;
    #pragma unroll
    for (int kin = 0; kin < 8; ++kin)
        u.h[kin] = __float2bfloat16(src[(size_t)kin * ldw]);
    const int slot = m * 4 + ((k2 + (m >> 2)) & 3);
    *(bf16x8*)(P + (size_t)tile * 4096 + slot * 8) = u.v;
}

// ---------------------------------------------------------------------------
// BIG bf16 MFMA GEMM: C[M,N] = A[M,2048] @ B (B tile-packed 128-wide tiles).
// Block tile 128x256, BK=32, 256 thr / 4 waves, wave tile 64x128 (acc 4x8).
// Wave-tile aspect raises FLOP/LDS-byte 1.33x vs 64x64 (reads 48KB vs 64KB
// per block-K-step at 2x FLOPs). 3-slot LDS ring (72KB), depth-2 prefetch,
// raw s_barrier + counted vmcnt(6) (6 staging loads per K-step stay in
// flight ACROSS barriers; vmcnt(0) only at final tile). 2 blocks/CU
// (launch_bounds(256,2): VGPR<=256, LDS 144KB).
// Ledger: stage(t+2)->slot (t+2)%3 issued after barrier(t); that slot's
// last readers (iter t-1) completed their ds_reads before barrier(t)
// (MFMA lgkmcnt dependency precedes barrier in program order).
// EPI: 0 -> C bf16 = acc ; 1 -> C fp32 = acc + Sf ; 2 -> C fp32 += acc
//      3 -> C bf16 = silu(Sb) * acc   (SwiGLU fusion; Sb bf16, may alias C)
// ---------------------------------------------------------------------------
template <int EPI>
__global__ __launch_bounds__(256, 2) void mfma_gemm_big(
    const __hip_bfloat16* __restrict__ A,
    const __hip_bfloat16* __restrict__ BP,
    const void* __restrict__ S,
    void* __restrict__ Cout,
    int ldc) {
    __shared__ __align__(16) __hip_bfloat16 Asb[3][4096];   // 3 x 8 KB
    __shared__ __align__(16) __hip_bfloat16 Bsb[3][8192];   // 3 x 16 KB
    const int tid  = threadIdx.x;
    const int lane = tid & 63;
    const int wave = tid >> 6;           // 0..3
    const int quad = lane >> 4;
    const int l16  = lane & 15;
    // XCD swizzle (bijective: nwg % 8 == 0 for every launch here: 8*98=784)
    const int nbx = gridDim.x;
    const int nwg = nbx * gridDim.y;
    int flat = blockIdx.y * nbx + blockIdx.x;
    flat = (flat & 7) * (nwg >> 3) + (flat >> 3);
    const int bxi = flat % nbx;
    const int byi = flat / nbx;
    const int bm = byi * 128;
    const int bn = bxi * 256;
    const int wm = (wave & 1) * 64;      // waves: 2m x 2n over 128x256
    const int wn = (wave >> 1) * 128;
    // A staging: lane t -> slot t (per 64-row half): row = h*64 + (t>>2),
    // source k-chunk kc = ((t&3)-(t>>4))&3 (swizzle-consistent, coalesced)
    const int kcA = ((tid & 3) - (tid >> 4)) & 3;
    const __hip_bfloat16* pA = A + (size_t)(bm + (tid >> 2)) * 2048 + kcA * 8;
    const __hip_bfloat16* pB = BP + (size_t)(2 * bxi) * 262144 + tid * 8;
    const int wb = wave * 512;           // wave-uniform LDS dest offset (elems)
    const int sw = (quad + (l16 >> 2)) & 3;   // read-side swizzle

    f32x4 acc[4][8] = {};
    // prologue: tiles 0,1 in flight (12 loads outstanding)
    #pragma unroll
    for (int t = 0; t < 2; ++t) {
        gload_lds16(pA + t * 32,                     &Asb[t][wb]);
        gload_lds16(pA + 131072 + t * 32,            &Asb[t][2048 + wb]);
        const __hip_bfloat16* b2 = pB + (size_t)t * 4096;
        gload_lds16(b2,                              &Bsb[t][wb]);
        gload_lds16(b2 + 2048,                       &Bsb[t][2048 + wb]);
        gload_lds16(b2 + 262144,                     &Bsb[t][4096 + wb]);
        gload_lds16(b2 + 264192,                     &Bsb[t][6144 + wb]);
    }
    int slot = 0;
    for (int t = 0; t < 64; ++t) {
        if (t < 63) asm volatile("s_waitcnt vmcnt(6)" ::: "memory");
        else        asm volatile("s_waitcnt vmcnt(0)" ::: "memory");
        __builtin_amdgcn_s_barrier();
        __builtin_amdgcn_sched_barrier(0);
        if (t + 2 < 64) {
            int s2 = slot + 2; if (s2 >= 3) s2 -= 3;
            const size_t kn = (size_t)(t + 2);
            gload_lds16(pA + kn * 32,                &Asb[s2][wb]);
            gload_lds16(pA + 131072 + kn * 32,       &Asb[s2][2048 + wb]);
            const __hip_bfloat16* b2 = pB + kn * 4096;
            gload_lds16(b2,                          &Bsb[s2][wb]);
            gload_lds16(b2 + 2048,                   &Bsb[s2][2048 + wb]);
            gload_lds16(b2 + 262144,                 &Bsb[s2][4096 + wb]);
            gload_lds16(b2 + 264192,                 &Bsb[s2][6144 + wb]);
        }
        const bf16x8* Af = (const bf16x8*)Asb[slot];
        const bf16x8* Bf = (const bf16x8*)&Bsb[slot][(wn >> 7) * 4096];
        bf16x8 av[4], bv[8];
        #pragma unroll
        for (int i = 0; i < 4; ++i)
            av[i] = Af[(wm + i * 16 + l16) * 4 + sw];
        #pragma unroll
        for (int i = 0; i < 8; ++i)
            bv[i] = Bf[(i * 16 + l16) * 4 + sw];
        __builtin_amdgcn_s_setprio(1);
        #pragma unroll
        for (int mi = 0; mi < 4; ++mi)
            #pragma unroll
            for (int ni = 0; ni < 8; ++ni)
                acc[mi][ni] = __builtin_amdgcn_mfma_f32_16x16x32_bf16(
                    av[mi], bv[ni], acc[mi][ni], 0, 0, 0);
        __builtin_amdgcn_s_setprio(0);
        ++slot; if (slot == 3) slot = 0;
    }
    // epilogue: C[row = bm+wm+mi*16+quad*4+r][col = bn+wn+ni*16+l16]
    #pragma unroll
    for (int mi = 0; mi < 4; ++mi) {
        #pragma unroll
        for (int ni = 0; ni < 8; ++ni) {
            const int col = bn + wn + ni * 16 + l16;
            #pragma unroll
            for (int r = 0; r < 4; ++r) {
                const int row = bm + wm + mi * 16 + quad * 4 + r;
                const size_t off = (size_t)row * ldc + col;
                const float vv = acc[mi][ni][r];
                if (EPI == 0)      ((__hip_bfloat16*)Cout)[off] = __float2bfloat16(vv);
                else if (EPI == 1) ((float*)Cout)[off] = vv + ((const float*)S)[off];
                else if (EPI == 2) ((float*)Cout)[off] += vv;
                else {
                    const float g = __bfloat162float(((const __hip_bfloat16*)S)[off]);
                    ((__hip_bfloat16*)Cout)[off] =
                        __float2bfloat16(g / (1.f + __expf(-g)) * vv);
                }
            }
        }
    }
}

// ---------------------------------------------------------------------------
// SMALL bf16 MFMA GEMM (N=512 K/V projections): 128x128 tile, BK=32, 4 waves
// of 64x64. Verified structure from previous round, unchanged.
// ---------------------------------------------------------------------------
template <int EPI>
__global__ __launch_bounds__(256) void mfma_gemm_kernel(
    const __hip_bfloat16* __restrict__ A,
    const __hip_bfloat16* __restrict__ BP,
    const void* __restrict__ S,
    void* __restrict__ Cout,
    int ldc) {
    __shared__ __align__(16) __hip_bfloat16 Asb[3][4096];   // 3 x 8 KB
    __shared__ __align__(16) __hip_bfloat16 Bsb[3][4096];   // 3 x 8 KB
    const int tid  = threadIdx.x;
    const int lane = tid & 63;
    const int wave = tid >> 6;
    const int quad = lane >> 4;
    const int l16  = lane & 15;
    const int nbx = gridDim.x;
    const int nwg = nbx * gridDim.y;
    int flat = blockIdx.y * nbx + blockIdx.x;
    flat = (flat & 7) * (nwg >> 3) + (flat >> 3);
    const int bxi = flat % nbx;
    const int byi = flat / nbx;
    const int bm = byi * 128;
    const int bn = bxi * 128;
    const int wm = (wave >> 1) * 64;
    const int wn = (wave & 1) * 64;
    const int kcA = ((tid & 3) - (tid >> 4)) & 3;
    const __hip_bfloat16* pA0 = A + (size_t)(bm + (tid >> 2)) * 2048 + kcA * 8;
    const __hip_bfloat16* pA1 = pA0 + (size_t)64 * 2048;
    const __hip_bfloat16* pB  = BP + (size_t)bxi * 262144 + tid * 8;
    const int wb = wave * 512;
    const int sw = (quad + (l16 >> 2)) & 3;

    f32x4 acc[4][4] = {};
    {
        gload_lds16(pA0,         &Asb[0][wb]);
        gload_lds16(pA1,         &Asb[0][2048 + wb]);
        gload_lds16(pB,          &Bsb[0][wb]);
        gload_lds16(pB + 2048,   &Bsb[0][2048 + wb]);
        gload_lds16(pA0 + 32,    &Asb[1][wb]);
        gload_lds16(pA1 + 32,    &Asb[1][2048 + wb]);
        gload_lds16(pB + 4096,   &Bsb[1][wb]);
        gload_lds16(pB + 6144,   &Bsb[1][2048 + wb]);
    }
    int slot = 0;
    for (int t = 0; t < 64; ++t) {
        if (t < 63) asm volatile("s_waitcnt vmcnt(4)" ::: "memory");
        else        asm volatile("s_waitcnt vmcnt(0)" ::: "memory");
        __builtin_amdgcn_s_barrier();
        __builtin_amdgcn_sched_barrier(0);
        if (t + 2 < 64) {
            int s2 = slot + 2; if (s2 >= 3) s2 -= 3;
            const int kn = (t + 2) * 32;
            const __hip_bfloat16* b2 = pB + (size_t)(t + 2) * 4096;
            gload_lds16(pA0 + kn,   &Asb[s2][wb]);
            gload_lds16(pA1 + kn,   &Asb[s2][2048 + wb]);
            gload_lds16(b2,         &Bsb[s2][wb]);
            gload_lds16(b2 + 2048,  &Bsb[s2][2048 + wb]);
        }
        const bf16x8* Af = (const bf16x8*)Asb[slot];
        const bf16x8* Bf = (const bf16x8*)Bsb[slot];
        bf16x8 av[4], bv[4];
        #pragma unroll
        for (int i = 0; i < 4; ++i) {
            av[i] = Af[(wm + i * 16 + l16) * 4 + sw];
            bv[i] = Bf[(wn + i * 16 + l16) * 4 + sw];
        }
        __builtin_amdgcn_s_setprio(1);
        #pragma unroll
        for (int tm = 0; tm < 4; ++tm)
            #pragma unroll
            for (int tn2 = 0; tn2 < 4; ++tn2)
                acc[tm][tn2] = __builtin_amdgcn_mfma_f32_16x16x32_bf16(
                    av[tm], bv[tn2], acc[tm][tn2], 0, 0, 0);
        __builtin_amdgcn_s_setprio(0);
        ++slot; if (slot == 3) slot = 0;
    }
    #pragma unroll
    for (int tm = 0; tm < 4; ++tm) {
        #pragma unroll
        for (int tn2 = 0; tn2 < 4; ++tn2) {
            const int col = bn + wn + tn2 * 16 + l16;
            #pragma unroll
            for (int r = 0; r < 4; ++r) {
                const int row = bm + wm + tm * 16 + quad * 4 + r;
                const size_t off = (size_t)row * ldc + col;
                const float vv = acc[tm][tn2][r];
                if (EPI == 0)      ((__hip_bfloat16*)Cout)[off] = __float2bfloat16(vv);
                else if (EPI == 1) ((float*)Cout)[off] = vv + ((const float*)S)[off];
                else if (EPI == 2) ((float*)Cout)[off] += vv;
                else {
                    const float g = __bfloat162float(((const __hip_bfloat16*)S)[off]);
                    ((__hip_bfloat16*)Cout)[off] =
                        __float2bfloat16(g / (1.f + __expf(-g)) * vv);
                }
            }
        }
    }
}

// ---------------------------------------------------------------------------
// RMSNorm fp32 in -> bf16 out. One block per token row.
// ---------------------------------------------------------------------------
__global__ __launch_bounds__(256) void rmsnorm_bf16_kernel(const float* __restrict__ x,
                                                           const float* __restrict__ w,
                                                           __hip_bfloat16* __restrict__ y) {
    const int row = blockIdx.x;
    const float* xr = x + (size_t)row * DMODEL;
    __hip_bfloat16* yr = y + (size_t)row * DMODEL;
    const int t = threadIdx.x;
    float4 v0 = ((const float4*)xr)[t];
    float4 v1 = ((const float4*)xr)[t + 256];
    float ss = v0.x*v0.x + v0.y*v0.y + v0.z*v0.z + v0.w*v0.w
             + v1.x*v1.x + v1.y*v1.y + v1.z*v1.z + v1.w*v1.w;
    #pragma unroll
    for (int off = 32; off; off >>= 1) ss += __shfl_xor(ss, off);
    __shared__ float red[4];
    if ((t & 63) == 0) red[t >> 6] = ss;
    __syncthreads();
    const float rs = rsqrtf((red[0] + red[1] + red[2] + red[3]) * (1.0f / DMODEL) + 1e-5f);
    float4 w0 = ((const float4*)w)[t];
    float4 w1 = ((const float4*)w)[t + 256];
    __hip_bfloat162 a, b, c, d;
    a.x = __float2bfloat16(v0.x * rs * w0.x); a.y = __float2bfloat16(v0.y * rs * w0.y);
    b.x = __float2bfloat16(v0.z * rs * w0.z); b.y = __float2bfloat16(v0.w * rs * w0.w);
    c.x = __float2bfloat16(v1.x * rs * w1.x); c.y = __float2bfloat16(v1.y * rs * w1.y);
    d.x = __float2bfloat16(v1.z * rs * w1.z); d.y = __float2bfloat16(v1.w * rs * w1.w);
    __hip_bfloat162* o0 = (__hip_bfloat162*)&yr[4 * t];
    o0[0] = a; o0[1] = b;
    __hip_bfloat162* o1 = (__hip_bfloat162*)&yr[1024 + 4 * t];
    o1[0] = c; o1[1] = d;
}

// ---------------------------------------------------------------------------
// RoPE in-place on bf16. x: [NT, nh, 64]; pair (i, i+32), angle t*500000^(-i/32)
// ---------------------------------------------------------------------------
__global__ __launch_bounds__(256) void rope_bf16_kernel(__hip_bfloat16* __restrict__ x,
                                                        int nh, int total) {
    const int idx = blockIdx.x * 256 + threadIdx.x;
    if (idx >= total) return;
    const int i = idx & 31;
    const int head_tok = idx >> 5;
    const int t = (head_tok / nh) % TSEQ;
    const float f = (float)t * powf(500000.0f, -(float)i * (1.0f / 32.0f));
    const float c = cosf(f), s = sinf(f);
    __hip_bfloat16* p = x + (size_t)head_tok * HDIM + i;
    const float x1 = __bfloat162float(p[0]), x2 = __bfloat162float(p[32]);
    p[0]  = __float2bfloat16(x1 * c - x2 * s);
    p[32] = __float2bfloat16(x2 * c + x1 * s);
}

// ---------------------------------------------------------------------------
// MFMA GQA causal attention. One block per (b, kvh); 8 waves (512 thr).
// ---------------------------------------------------------------------------
__global__ __launch_bounds__(512) void attn_mfma_kernel(const __hip_bfloat16* __restrict__ q,
                                                        const __hip_bfloat16* __restrict__ k,
                                                        const __hip_bfloat16* __restrict__ v,
                                                        __hip_bfloat16* __restrict__ o) {
    __shared__ __align__(16) __hip_bfloat16 Kl[208 * 64];    // swizzled (26.6 KB)
    __shared__ __align__(16) __hip_bfloat16 Vt[64 * 232];    // [hd][232] (29.7 KB)
    __shared__ __align__(16) __hip_bfloat16 Ps[8][16 * 232]; // per-wave P (59.4 KB)
    const int b = blockIdx.x >> 3;
    const int kvh = blockIdx.x & 7;
    const int tid = threadIdx.x, wave = tid >> 6, lane = tid & 63;
    const int quad = lane >> 4, l16 = lane & 15;

    for (int idx = tid; idx < 208 * 8; idx += 512) {
        const int tk = idx >> 3, c = idx & 7;
        bf16x8 val = {};
        if (tk < 196) val = *(const bf16x8*)&k[((size_t)(b * 196 + tk) * 8 + kvh) * 64 + c * 8];
        *(bf16x8*)&Kl[tk * 64 + ((c + (tk & 7)) & 7) * 8] = val;
    }
    for (int idx = tid; idx < 224 * 64; idx += 512) {
        const int tk = idx >> 6, hd = idx & 63;
        float val = 0.f;
        if (tk < 196) val = __bfloat162float(v[((size_t)(b * 196 + tk) * 8 + kvh) * 64 + hd]);
        Vt[hd * 232 + tk] = __float2bfloat16(val);
    }
    __syncthreads();

    const int h = kvh * 4 + (wave & 3);
    const int swk0 = l16 & 7;
    __hip_bfloat16* pw = &Ps[wave][0];
    for (int rt = wave >> 2; rt < 13; rt += 2) {
        const size_t qoff = ((size_t)(b * 196 + rt * 16 + l16) * 32 + h) * 64 + quad * 8;
        const bf16x8 qa0 = *(const bf16x8*)&q[qoff];
        const bf16x8 qa1 = *(const bf16x8*)&q[qoff + 32];
        f32x4 sf[13];
        #pragma unroll
        for (int ct = 0; ct < 13; ++ct) {
            if (ct <= rt) {
                const int tkr = ct * 16 + l16;
                const bf16x8 k0 = *(const bf16x8*)&Kl[tkr * 64 + ((quad + swk0) & 7) * 8];
                const bf16x8 k1 = *(const bf16x8*)&Kl[tkr * 64 + ((quad + 4 + swk0) & 7) * 8];
                f32x4 s = {};
                s = __builtin_amdgcn_mfma_f32_16x16x32_bf16(qa0, k0, s, 0, 0, 0);
                s = __builtin_amdgcn_mfma_f32_16x16x32_bf16(qa1, k1, s, 0, 0, 0);
                sf[ct] = s;
            }
        }
        float mrow[4] = {-INFINITY, -INFINITY, -INFINITY, -INFINITY};
        #pragma unroll
        for (int ct = 0; ct < 13; ++ct) {
            if (ct <= rt) {
                #pragma unroll
                for (int r = 0; r < 4; ++r) {
                    const int row = rt * 16 + quad * 4 + r;
                    const int col = ct * 16 + l16;
                    float s = sf[ct][r] * 0.125f;
                    if (col > row) s = -INFINITY;
                    sf[ct][r] = s;
                    mrow[r] = fmaxf(mrow[r], s);
                }
            }
        }
        #pragma unroll
        for (int r = 0; r < 4; ++r) {
            float m = mrow[r];
            m = fmaxf(m, __shfl_xor(m, 1));
            m = fmaxf(m, __shfl_xor(m, 2));
            m = fmaxf(m, __shfl_xor(m, 4));
            m = fmaxf(m, __shfl_xor(m, 8));
            mrow[r] = m;
        }
        float ls[4] = {0.f, 0.f, 0.f, 0.f};
        #pragma unroll
        for (int ct = 0; ct < 13; ++ct) {
            if (ct <= rt) {
                #pragma unroll
                for (int r = 0; r < 4; ++r) {
                    const float p = __expf(sf[ct][r] - mrow[r]);
                    sf[ct][r] = p;
                    ls[r] += p;
                }
            }
        }
        #pragma unroll
        for (int r = 0; r < 4; ++r) {
            float s = ls[r];
            s += __shfl_xor(s, 1);
            s += __shfl_xor(s, 2);
            s += __shfl_xor(s, 4);
            s += __shfl_xor(s, 8);
            ls[r] = s;
        }
        #pragma unroll
        for (int ct = 0; ct < 13; ++ct) {
            if (ct <= rt) {
                #pragma unroll
                for (int r = 0; r < 4; ++r)
                    pw[(quad * 4 + r) * 232 + ct * 16 + l16] = __float2bfloat16(sf[ct][r]);
            }
        }
        if (!(rt & 1)) {
            const int ct = rt + 1;
            #pragma unroll
            for (int r = 0; r < 4; ++r)
                pw[(quad * 4 + r) * 232 + ct * 16 + l16] = __float2bfloat16(0.f);
        }
        asm volatile("s_waitcnt lgkmcnt(0)" ::: "memory");
        const int nkt = (rt >> 1) + 1;
        f32x4 of[4] = {};
        #pragma unroll
        for (int ktv = 0; ktv < 7; ++ktv) {
            if (ktv < nkt) {
                const bf16x8 pa = *(const bf16x8*)&pw[l16 * 232 + ktv * 32 + quad * 8];
                #pragma unroll
                for (int co = 0; co < 4; ++co) {
                    const bf16x8 vf = *(const bf16x8*)&Vt[(co * 16 + l16) * 232 + ktv * 32 + quad * 8];
                    of[co] = __builtin_amdgcn_mfma_f32_16x16x32_bf16(pa, vf, of[co], 0, 0, 0);
                }
            }
        }
        #pragma unroll
        for (int r = 0; r < 4; ++r) {
            const int row = rt * 16 + quad * 4 + r;
            if (row < 196) {
                const float inv = 1.f / ls[r];
                #pragma unroll
                for (int co = 0; co < 4; ++co)
                    o[((size_t)(b * 196 + row) * 32 + h) * 64 + co * 16 + l16] =
                        __float2bfloat16(of[co][r] * inv);
            }
        }
    }
}

// ---------------------------------------------------------------------------
// Head projection (fp32, precision-critical path): zp = (x2 * w_norm) @ Wp.
// ---------------------------------------------------------------------------
__global__ __launch_bounds__(256) void sgemm_head_kernel(const float* __restrict__ A,
                                                         const float* __restrict__ wn_,
                                                         const float* __restrict__ B,
                                                         float* __restrict__ C,
                                                         int K, int lda, int ldb, int ldc) {
    __shared__ float As[16][68];
    __shared__ float Bs[16][64];
    const int tid = threadIdx.x;
    const int tx = tid & 15, ty = tid >> 4;
    const int bm = blockIdx.y * 64;
    const int bn = blockIdx.x * 64;
    const int ar = tid >> 2, ac = (tid & 3) * 4;
    const int br = tid >> 4, bc = (tid & 15) * 4;
    float acc[4][4] = {};
    for (int k0 = 0; k0 < K; k0 += 16) {
        float4 av = *(const float4*)&A[(size_t)(bm + ar) * lda + k0 + ac];
        float4 wv = *(const float4*)&wn_[k0 + ac];
        float4 bv = *(const float4*)&B[(size_t)(k0 + br) * ldb + bn + bc];
        av.x *= wv.x; av.y *= wv.y; av.z *= wv.z; av.w *= wv.w;
        __syncthreads();
        As[ac + 0][ar] = av.x; As[ac + 1][ar] = av.y;
        As[ac + 2][ar] = av.z; As[ac + 3][ar] = av.w;
        *(float4*)&Bs[br][bc] = bv;
        __syncthreads();
        #pragma unroll
        for (int kk = 0; kk < 16; ++kk) {
            float4 a = *(const float4*)&As[kk][ty * 4];
            float4 b = *(const float4*)&Bs[kk][tx * 4];
            acc[0][0] += a.x * b.x; acc[0][1] += a.x * b.y; acc[0][2] += a.x * b.z; acc[0][3] += a.x * b.w;
            acc[1][0] += a.y * b.x; acc[1][1] += a.y * b.y; acc[1][2] += a.y * b.z; acc[1][3] += a.y * b.w;
            acc[2][0] += a.z * b.x; acc[2][1] += a.z * b.y; acc[2][2] += a.z * b.z; acc[2][3] += a.z * b.w;
            acc[3][0] += a.w * b.x; acc[3][1] += a.w * b.y; acc[3][2] += a.w * b.z; acc[3][3] += a.w * b.w;
        }
    }
    #pragma unroll
    for (int i = 0; i < 4; ++i) {
        const size_t off = (size_t)(bm + ty * 4 + i) * ldc + bn + tx * 4;
        *(float4*)&C[off] = make_float4(acc[i][0], acc[i][1], acc[i][2], acc[i][3]);
    }
}

// ---------------------------------------------------------------------------
// zq = normalize(query @ Wqh) : 64 blocks x 128 threads (fp32)
// ---------------------------------------------------------------------------
__global__ __launch_bounds__(128) void zq_kernel(const float* __restrict__ query,
                                                 const float* __restrict__ Wqh,
                                                 float* __restrict__ zq) {
    const int b = blockIdx.x, j = threadIdx.x;
    const float* qr = query + (size_t)b * QDIMC;
    float acc = 0.f;
    for (int kk = 0; kk < QDIMC; ++kk) acc += qr[kk] * Wqh[(size_t)kk * PDIMC + j];
    float ss = acc * acc;
    #pragma unroll
    for (int off = 32; off; off >>= 1) ss += __shfl_xor(ss, off);
    __shared__ float red[2];
    if ((j & 63) == 0) red[j >> 6] = ss;
    __syncthreads();
    zq[(size_t)b * PDIMC + j] = acc * rsqrtf(red[0] + red[1]);
}

// ---------------------------------------------------------------------------
// out[b,t] = dot(normalize(zp[b,t]), zq[b]) * scale + bias : 1 block/token
// ---------------------------------------------------------------------------
__global__ __launch_bounds__(128) void head_kernel(const float* __restrict__ zp,
                                                   const float* __restrict__ zq,
                                                   const float* __restrict__ scale,
                                                   const float* __restrict__ bias,
                                                   float* __restrict__ out) {
    const int row = blockIdx.x;
    const int b = row / TSEQ;
    const int j = threadIdx.x;
    const float zpv = zp[(size_t)row * PDIMC + j];
    const float zqv = zq[(size_t)b * PDIMC + j];
    float ss = zpv * zpv, dd = zpv * zqv;
    #pragma unroll
    for (int off = 32; off; off >>= 1) { ss += __shfl_xor(ss, off); dd += __shfl_xor(dd, off); }
    __shared__ float rs2[2], rd2[2];
    if ((j & 63) == 0) { rs2[j >> 6] = ss; rd2[j >> 6] = dd; }
    __syncthreads();
    if (j == 0)
        out[row] = (rd2[0] + rd2[1]) * rsqrtf(rs2[0] + rs2[1]) * scale[0] + bias[0];
}

// ---------------------------------------------------------------------------
extern "C" void kernel_launch(void* const* d_in, const int* in_sizes, int n_in,
                              void* d_out, int out_size, void* d_ws, size_t ws_size,
                              hipStream_t stream) {
    const float* x       = (const float*)d_in[0];
    const float* query   = (const float*)d_in[1];
    const float* Wq      = (const float*)d_in[2];
    const float* Wk      = (const float*)d_in[3];
    const float* Wv      = (const float*)d_in[4];
    const float* Wo      = (const float*)d_in[5];
    const float* Wgate   = (const float*)d_in[6];
    const float* Wup     = (const float*)d_in[7];
    const float* Wdown   = (const float*)d_in[8];
    const float* w_ln_in = (const float*)d_in[9];
    const float* w_ln_po = (const float*)d_in[10];
    const float* w_norm  = (const float*)d_in[11];
    const float* Wp      = (const float*)d_in[12];
    const float* Wqh     = (const float*)d_in[13];
    const float* scale   = (const float*)d_in[14];
    const float* bias    = (const float*)d_in[15];
    float* out = (float*)d_out;

    // Workspace: 243.8 MB total (< proven 245 MB budget)
    char* ws = (char*)d_ws;
    __hip_bfloat16* R1 = (__hip_bfloat16*)ws;                 // 51.38MB: h -> o -> h2
    __hip_bfloat16* R2 = (__hip_bfloat16*)(ws + 51380224);    // 51.38MB: q -> g/act -> zp,zq
    __hip_bfloat16* R3 = (__hip_bfloat16*)(ws + 102760448);   // 12.85MB: k
    __hip_bfloat16* R4 = (__hip_bfloat16*)(ws + 115605504);   // 12.85MB: v
    float*          x1 = (float*)(ws + 128450560);            // 102.76MB: fp32 residual
    __hip_bfloat16* packW = (__hip_bfloat16*)(ws + 231211008); // 12.58MB region (use <=8.4MB)
    float* zp = (float*)(ws + 51380224);                // over R2 (act dead at head time)
    float* zq = zp + (size_t)NT * PDIMC;

    // --- self-attn sublayer ---
    rmsnorm_bf16_kernel<<<NT, 256, 0, stream>>>(x, w_ln_in, R1);
    pack_cast_kernel<<<2048, 256, 0, stream>>>(Wq, packW, 2048);
    mfma_gemm_big<0><<<dim3(8, 98), 256, 0, stream>>>(R1, packW, nullptr, R2, 2048);
    pack_cast_kernel<<<512, 256, 0, stream>>>(Wk, packW, 512);
    mfma_gemm_kernel<0><<<dim3(4, 98), 256, 0, stream>>>(R1, packW, nullptr, R3, 512);
    pack_cast_kernel<<<512, 256, 0, stream>>>(Wv, packW, 512);
    mfma_gemm_kernel<0><<<dim3(4, 98), 256, 0, stream>>>(R1, packW, nullptr, R4, 512);
    rope_bf16_kernel<<<(NT * NH * 32) / 256, 256, 0, stream>>>(R2, NH, NT * NH * 32);
    rope_bf16_kernel<<<(NT * NKVH * 32) / 256, 256, 0, stream>>>(R3, NKVH, NT * NKVH * 32);
    attn_mfma_kernel<<<BATCH * NKVH, 512, 0, stream>>>(R2, R3, R4, R1); // o -> R1
    pack_cast_kernel<<<2048, 256, 0, stream>>>(Wo, packW, 2048);
    mfma_gemm_big<1><<<dim3(8, 98), 256, 0, stream>>>(R1, packW, x, x1, 2048);
    // --- MLP sublayer (SwiGLU), I chunked by 2048, JIT weight pack ---
    rmsnorm_bf16_kernel<<<NT, 256, 0, stream>>>(x1, w_ln_po, R1);    // h2 -> R1
    for (int c = 0; c < 4; ++c) {
        pack_cast_kernel<<<2048, 256, 0, stream>>>(Wgate + (size_t)c * 2048, packW, 8192);
        mfma_gemm_big<0><<<dim3(8, 98), 256, 0, stream>>>(R1, packW, nullptr, R2, 2048);
        pack_cast_kernel<<<2048, 256, 0, stream>>>(Wup + (size_t)c * 2048, packW, 8192);
        mfma_gemm_big<3><<<dim3(8, 98), 256, 0, stream>>>(R1, packW, R2, R2, 2048);
        pack_cast_kernel<<<2048, 256, 0, stream>>>(Wdown + (size_t)c * 2048 * DMODEL, packW, 2048);
        mfma_gemm_big<2><<<dim3(8, 98), 256, 0, stream>>>(R2, packW, nullptr, x1, 2048);
    }
    // --- head (fp32; final rmsnorm's row scale cancels under normalize) ---
    sgemm_head_kernel<<<dim3(2, 196), 256, 0, stream>>>(x1, w_norm, Wp, zp, 2048, 2048, PDIMC, PDIMC);
    zq_kernel<<<BATCH, 128, 0, stream>>>(query, Wqh, zq);
    head_kernel<<<NT, 128, 0, stream>>>(zp, zq, scale, bias, out);
}